// Round 4
// baseline (354.724 us; speedup 1.0000x reference)
//
#include <hip/hip_runtime.h>

typedef unsigned short u16;
typedef unsigned int u32;
using bf16x8 = __attribute__((ext_vector_type(8))) short;
using f32x4  = __attribute__((ext_vector_type(4))) float;

__device__ __forceinline__ u16 f2bf(float f) {
  u32 u = __float_as_uint(f);
  return (u16)((u + 0x7FFFu + ((u >> 16) & 1u)) >> 16);
}
__device__ __forceinline__ float bf2f(u16 h) {
  return __uint_as_float(((u32)h) << 16);
}

// ---------------- conv 3x3, 3->64, SAME, ReLU; out fmap[y][x][c] bf16 --------
__global__ __launch_bounds__(256) void conv3x3_relu_k(
    const float* __restrict__ img, const float* __restrict__ w,
    const float* __restrict__ bias, u16* __restrict__ fmap) {
  int p = blockIdx.x * 256 + threadIdx.x;  // 0..262143
  int y = p >> 9, x = p & 511;
  float v[27];
#pragma unroll
  for (int ci = 0; ci < 3; ++ci)
#pragma unroll
    for (int ky = 0; ky < 3; ++ky)
#pragma unroll
      for (int kx = 0; kx < 3; ++kx) {
        int yy = y + ky - 1, xx = x + kx - 1;
        bool ok = (yy >= 0) && (yy < 512) && (xx >= 0) && (xx < 512);
        v[(ci * 3 + ky) * 3 + kx] = ok ? img[ci * 262144 + yy * 512 + xx] : 0.f;
      }
  float acc[64];
#pragma unroll
  for (int co = 0; co < 64; ++co) {
    float s = bias[co];
#pragma unroll
    for (int q = 0; q < 27; ++q) s = fmaf(w[co * 27 + q], v[q], s);
    acc[co] = fmaxf(s, 0.f);
  }
  uint4* dst = (uint4*)((u32*)fmap + (size_t)p * 32);
#pragma unroll
  for (int q = 0; q < 8; ++q) {
    uint4 d;
    d.x = (u32)f2bf(acc[8 * q + 0]) | ((u32)f2bf(acc[8 * q + 1]) << 16);
    d.y = (u32)f2bf(acc[8 * q + 2]) | ((u32)f2bf(acc[8 * q + 3]) << 16);
    d.z = (u32)f2bf(acc[8 * q + 4]) | ((u32)f2bf(acc[8 * q + 5]) << 16);
    d.w = (u32)f2bf(acc[8 * q + 6]) | ((u32)f2bf(acc[8 * q + 7]) << 16);
    dst[q] = d;
  }
}

// ---------------- RoI max pool: block per roi; feat[n][c*49+py*7+px] bf16 ----
__global__ __launch_bounds__(256) void roipool_k(
    const u16* __restrict__ fmap, const int* __restrict__ regions,
    u16* __restrict__ feat) {
  int n = blockIdx.x, t = threadIdx.x;
  uint4* fdst = (uint4*)(feat + (size_t)n * 3136);  // 392 uint4 per row
  if (n >= 2000) {  // zero pad rows so GEMM needs no edge masking
    uint4 z; z.x = z.y = z.z = z.w = 0u;
    fdst[t % 392] = z;
    int t2 = t + 256; if (t2 < 392) fdst[t2] = z;
    if (t < 392) fdst[t] = z;
    return;
  }
  int r0 = regions[2 * n], c0 = regions[2 * n + 1];
  __shared__ uint2 rows_u2[1792];  // 4 rows x 28 x 64c bf16 = 14336 B
  __shared__ uint4 frow4[392];     // 3136 bf16 = 6272 B
  u16* rows = (u16*)rows_u2;
  u16* frow = (u16*)frow4;
  for (int py = 0; py < 7; ++py) {
#pragma unroll
    for (int q = 0; q < 7; ++q) {
      int cid = t + q * 256;           // 0..1791, 8B chunks
      int i = cid / 448, rem = cid % 448;
      int xo = rem >> 4, c4 = (rem & 15) << 2;
      int yy = r0 + py * 4 + i, xx = c0 + xo;
      rows_u2[cid] = *(const uint2*)(fmap + (((size_t)(yy * 512 + xx)) << 6) + c4);
    }
    __syncthreads();
#pragma unroll
    for (int h = 0; h < 2; ++h) {
      int o = t + h * 256;
      if (o < 448) {
        int c = o & 63, px = o >> 6;
        float best = -3.0e38f;
#pragma unroll
        for (int i = 0; i < 4; ++i)
#pragma unroll
          for (int j = 0; j < 4; ++j)
            best = fmaxf(best, bf2f(rows[(i * 28 + px * 4 + j) * 64 + c]));
        frow[c * 49 + py * 7 + px] = f2bf(best);
      }
    }
    __syncthreads();
  }
  if (t < 392) fdst[t] = frow4[t];
  int t2 = t + 256;
  if (t2 < 392) fdst[t2] = frow4[t2];
}

// ---------------- fp32 -> bf16 conversion (vectorized) -----------------------
__global__ __launch_bounds__(256) void f2bf_k(const float* __restrict__ in,
                                              u16* __restrict__ out, int n4) {
  int idx = blockIdx.x * 256 + threadIdx.x;
  int stride = gridDim.x * 256;
  for (int i = idx; i < n4; i += stride) {
    float4 v = ((const float4*)in)[i];
    uint2 o;
    o.x = (u32)f2bf(v.x) | ((u32)f2bf(v.y) << 16);
    o.y = (u32)f2bf(v.z) | ((u32)f2bf(v.w) << 16);
    ((uint2*)out)[i] = o;
  }
}

// ---------------- 8-wave 256x256 split-K bf16 GEMM (B^T), partials to fp32 P.
// P[m][n] += sum_{k in block's K-range} A[m][k]*B[n][k]   (atomic add)
// BM=BN=256, BK=64. 512 thr = 8 waves (2M x 4N), per-wave 128x64 output.
// 2 LDS buffers (128 KB), prefetch distance 1, 4 phases/K-tile (m201-style).
// T2 XOR-swizzle: LDS row r (128 B, 8 x 16B slots): phys slot = s ^ (r&7).
// grid = 256 blocks: 8 mb x 16 nb x 2 sk (with XCD-aware remap).
__global__ __launch_bounds__(512, 2) void gemm256_splitk_k(
    const u16* __restrict__ A, const u16* __restrict__ B,
    float* __restrict__ P, int N, int K, int NT0, int NT) {
  __shared__ uint4 lds4[8192];  // 131072 B = 2 x (A 32KB + B 32KB)
  char* ldsb = (char*)lds4;
  const int t = threadIdx.x;
  const int lane = t & 63, wv = t >> 6;
  const int wm = wv >> 2, wn = wv & 3;

  int bid = blockIdx.x;                      // grid must be exactly 256
  int swz = ((bid & 7) << 5) | (bid >> 3);   // XCD-contiguous remap (bijective)
  const int sk = swz >> 7;
  const int mb = swz & 7, nb = (swz >> 3) & 15;
  const int m0 = mb * 256, n0 = nb * 256;
  const int t0 = sk ? NT0 : 0;
  const int tend = sk ? NT : NT0;
  const int NTb = tend - t0;

  const u16* __restrict__ Ab = A + (size_t)m0 * K;
  const u16* __restrict__ Bb = B + (size_t)n0 * K;

  // staging: one sweep = 64 rows x 128 B (8 KB); thread t -> row t>>3, slot t&7.
  // Global slot pre-swizzled (involution), LDS dest linear.
  const int srow = t >> 3;
  const int sslot = (t & 7) ^ (srow & 7);
  const u16* pA = Ab + (size_t)srow * K + sslot * 8;
  const u16* pB = Bb + (size_t)srow * K + sslot * 8;
  const int dof = t * 16;

#define G2L(src, ldst)                                                        \
  __builtin_amdgcn_global_load_lds(                                          \
      (const __attribute__((address_space(1))) void*)(src),                  \
      (__attribute__((address_space(3))) void*)(ldst), 16, 0, 0)

  // fragment read offsets (swizzled): row16 = lane&15, sl = lane>>4
  const int row16 = lane & 15, sl = lane >> 4;
  const int sa = (sl ^ (row16 & 7)) << 4;
  const int aoffs0 = (wm * 128 + row16) * 128 + sa;
  const int aoffs1 = aoffs0 ^ 64;            // k-half 1: phys slot ^ 4
  const int boffs0 = (wn * 64 + row16) * 128 + sa;
  const int boffs1 = boffs0 ^ 64;

  f32x4 acc[8][4] = {};
  bf16x8 bfr[4][2], afr[2][2];

  // ---- prologue: stage tile t0 into buf 0
  {
    char* A0 = ldsb; char* B0 = ldsb + 32768;
    const size_t kof = (size_t)t0 * 64;
#pragma unroll
    for (int q = 0; q < 4; ++q) {
      G2L(pA + (size_t)(q * 64) * K + kof, A0 + q * 8192 + dof);
      G2L(pB + (size_t)(q * 64) * K + kof, B0 + q * 8192 + dof);
    }
  }
  asm volatile("s_waitcnt vmcnt(0)" ::: "memory");
  __builtin_amdgcn_s_barrier();

  for (int tt = 0; tt < NTb; ++tt) {
    char* Acur = ldsb + (tt & 1) * 65536;
    char* Bcur = Acur + 32768;
    char* Anx = ldsb + ((tt & 1) ^ 1) * 65536;
    char* Bnx = Anx + 32768;
    const bool pf = (tt + 1) < NTb;
    const size_t kofn = (size_t)(t0 + tt + 1) * 64;

#pragma unroll
    for (int p = 0; p < 4; ++p) {
      if (p == 0) {
#pragma unroll
        for (int j = 0; j < 4; ++j) {
          bfr[j][0] = *(const bf16x8*)(Bcur + boffs0 + j * 2048);
          bfr[j][1] = *(const bf16x8*)(Bcur + boffs1 + j * 2048);
        }
#pragma unroll
        for (int ii = 0; ii < 2; ++ii) {
          afr[ii][0] = *(const bf16x8*)(Acur + aoffs0 + ii * 2048);
          afr[ii][1] = *(const bf16x8*)(Acur + aoffs1 + ii * 2048);
        }
        if (pf) {
#pragma unroll
          for (int q = 0; q < 4; ++q) {
            G2L(pA + (size_t)(q * 64) * K + kofn, Anx + q * 8192 + dof);
            G2L(pB + (size_t)(q * 64) * K + kofn, Bnx + q * 8192 + dof);
          }
        }
      } else {
#pragma unroll
        for (int ii = 0; ii < 2; ++ii) {
          afr[ii][0] = *(const bf16x8*)(Acur + aoffs0 + (2 * p + ii) * 2048);
          afr[ii][1] = *(const bf16x8*)(Acur + aoffs1 + (2 * p + ii) * 2048);
        }
      }
      __builtin_amdgcn_s_barrier();
      asm volatile("s_waitcnt lgkmcnt(0)" ::: "memory");
      __builtin_amdgcn_sched_barrier(0);
      __builtin_amdgcn_s_setprio(1);
#pragma unroll
      for (int ii = 0; ii < 2; ++ii)
#pragma unroll
        for (int j = 0; j < 4; ++j) {
          acc[2 * p + ii][j] = __builtin_amdgcn_mfma_f32_16x16x32_bf16(
              afr[ii][0], bfr[j][0], acc[2 * p + ii][j], 0, 0, 0);
          acc[2 * p + ii][j] = __builtin_amdgcn_mfma_f32_16x16x32_bf16(
              afr[ii][1], bfr[j][1], acc[2 * p + ii][j], 0, 0, 0);
        }
      __builtin_amdgcn_s_setprio(0);
      if (p == 3 && pf)
        asm volatile("s_waitcnt vmcnt(0)" ::: "memory");  // next tile landed
      __builtin_amdgcn_s_barrier();
    }
  }
#undef G2L

  // ---- epilogue: atomic-add fp32 partials
#pragma unroll
  for (int i = 0; i < 8; ++i)
#pragma unroll
    for (int j = 0; j < 4; ++j) {
      const int cg = n0 + wn * 64 + j * 16 + row16;
#pragma unroll
      for (int r = 0; r < 4; ++r) {
        const int rg = m0 + wm * 128 + i * 16 + sl * 4 + r;
        atomicAdd(&P[(size_t)rg * N + cg], acc[i][j][r]);
      }
    }
}

// ---------------- finalize: H = bf16(relu(P + bias[col])), row-major 2048x4096
__global__ __launch_bounds__(256) void finalize_k(
    const float* __restrict__ P, const float* __restrict__ bias,
    u16* __restrict__ H, int total8) {
  int i = blockIdx.x * 256 + threadIdx.x;
  int stride = gridDim.x * 256;
  for (; i < total8; i += stride) {
    const float4* p4 = (const float4*)(P + (size_t)i * 8);
    float4 v0 = p4[0], v1 = p4[1];
    int col = (i * 8) & 4095;
    float4 b0 = *(const float4*)(bias + col);
    float4 b1 = *(const float4*)(bias + col + 4);
    float r0 = fmaxf(v0.x + b0.x, 0.f), r1 = fmaxf(v0.y + b0.y, 0.f);
    float r2 = fmaxf(v0.z + b0.z, 0.f), r3 = fmaxf(v0.w + b0.w, 0.f);
    float r4 = fmaxf(v1.x + b1.x, 0.f), r5 = fmaxf(v1.y + b1.y, 0.f);
    float r6 = fmaxf(v1.z + b1.z, 0.f), r7 = fmaxf(v1.w + b1.w, 0.f);
    uint4 o;
    o.x = (u32)f2bf(r0) | ((u32)f2bf(r1) << 16);
    o.y = (u32)f2bf(r2) | ((u32)f2bf(r3) << 16);
    o.z = (u32)f2bf(r4) | ((u32)f2bf(r5) << 16);
    o.w = (u32)f2bf(r6) | ((u32)f2bf(r7) << 16);
    ((uint4*)H)[i] = o;
  }
}

// ---------------- cls/bbox heads: block per roi, 10 dots of K=4096 -----------
__global__ __launch_bounds__(256) void heads_k(
    const u16* __restrict__ h2, const float* __restrict__ cw,
    const float* __restrict__ cb, const float* __restrict__ bw,
    const float* __restrict__ bb, float* __restrict__ out) {
  int m = blockIdx.x, t = threadIdx.x;
  const u16* hrow = h2 + (size_t)m * 4096;
  float p[10];
#pragma unroll
  for (int j = 0; j < 10; ++j) p[j] = 0.f;
  for (int k = t; k < 4096; k += 256) {
    float v = bf2f(hrow[k]);
    p[0] = fmaf(v, cw[k], p[0]);
    p[1] = fmaf(v, cw[4096 + k], p[1]);
#pragma unroll
    for (int j = 0; j < 8; ++j) p[2 + j] = fmaf(v, bw[j * 4096 + k], p[2 + j]);
  }
#pragma unroll
  for (int j = 0; j < 10; ++j)
#pragma unroll
    for (int off = 32; off > 0; off >>= 1) p[j] += __shfl_down(p[j], off);
  __shared__ float red[4][10];
  int lane = t & 63, wv = t >> 6;
  if (lane == 0) {
#pragma unroll
    for (int j = 0; j < 10; ++j) red[wv][j] = p[j];
  }
  __syncthreads();
  if (t < 10) {
    float s = red[0][t] + red[1][t] + red[2][t] + red[3][t];
    s += (t < 2) ? cb[t] : bb[t - 2];
    if (t < 2) out[m * 2 + t] = s;
    else out[4000 + m * 8 + (t - 2)] = s;
  }
}

extern "C" void kernel_launch(void* const* d_in, const int* in_sizes, int n_in,
                              void* d_out, int out_size, void* d_ws, size_t ws_size,
                              hipStream_t stream) {
  const float* img    = (const float*)d_in[0];
  const int*   regions= (const int*)d_in[1];
  const float* conv_w = (const float*)d_in[2];
  const float* conv_b = (const float*)d_in[3];
  const float* fc1_w  = (const float*)d_in[4];
  const float* fc1_b  = (const float*)d_in[5];
  const float* fc2_w  = (const float*)d_in[6];
  const float* fc2_b  = (const float*)d_in[7];
  const float* cls_w  = (const float*)d_in[8];
  const float* cls_b  = (const float*)d_in[9];
  const float* bbox_w = (const float*)d_in[10];
  const float* bbox_b = (const float*)d_in[11];
  float* out = (float*)d_out;

  char* ws = (char*)d_ws;
  // layout (bytes), total 105,644,032 (same footprint as before):
  //   [0, 33554432)          fmap [512][512][64] bf16; later h1=[0,16M), h2=[16M,32M)
  //   [33554432, 67108864)   feat [2048][3136] bf16 @33554432 (12.85 MB);
  //                          later w2b [4096][4096] bf16 occupies [33554432,67108864)
  //   [46399488, 72089600)   w1b  [4096][3136] bf16 (dead after fc1)
  //   [72089600, 105644032)  P1   [2048][4096] fp32 partials (33.55 MB)
  u16* fmap = (u16*)(ws);
  u16* h1   = (u16*)(ws);
  u16* h2   = (u16*)(ws + 16777216);
  u16* feat = (u16*)(ws + 33554432);
  u16* w1b  = (u16*)(ws + 46399488);
  u16* w2b  = (u16*)(ws + 33554432);   // reuses feat+w1b region after fc1
  float* P1 = (float*)(ws + 72089600);

  conv3x3_relu_k<<<1024, 256, 0, stream>>>(img, conv_w, conv_b, fmap);
  roipool_k<<<2048, 256, 0, stream>>>(fmap, regions, feat);
  f2bf_k<<<2048, 256, 0, stream>>>(fc1_w, w1b, 4096 * 3136 / 4);
  hipMemsetAsync(P1, 0, 33554432, stream);
  gemm256_splitk_k<<<256, 512, 0, stream>>>(feat, w1b, P1, 4096, 3136, 25, 49);
  finalize_k<<<2048, 256, 0, stream>>>(P1, fc1_b, h1, 1048576);
  f2bf_k<<<2048, 256, 0, stream>>>(fc2_w, w2b, 4096 * 4096 / 4);
  hipMemsetAsync(P1, 0, 33554432, stream);
  gemm256_splitk_k<<<256, 512, 0, stream>>>(h1, w2b, P1, 4096, 4096, 32, 64);
  finalize_k<<<2048, 256, 0, stream>>>(P1, fc2_b, h2, 1048576);
  heads_k<<<2000, 256, 0, stream>>>(h2, cls_w, cls_b, bbox_w, bbox_b, out);
}